// Round 4
// baseline (192.989 us; speedup 1.0000x reference)
//
#include <hip/hip_runtime.h>
#include <hip/hip_fp16.h>

#define HH 28
#define WW 28
#define NPIX 784
#define BLOCK 448            // 7 waves; lanes 0..391 compute, rest stage-only
#define PSTRIDE 37           // odd: base-slot residue mod 8 advances +1 per pixel
                             // even across row wraps (37-28=9 == +1 mod 8)
#define PROWS 24             // 20 staged rows + 4-row jitter/tap margin
#define TSLOTS (PROWS * PSTRIDE)   // 888 slots * 16B = 14208 B; dbuf = 28416 B

// Round-4 change: no pipe was saturated (LDS 59%, VALU 34%, HBM 38%) at 64us
// -> latency/lockstep bound, not throughput bound. Restructure for overlap:
//  - 2 horizontal bands (rows 0-13 / 14-27), 7-wave blocks, 4 independent
//    blocks/CU (28 waves) instead of 2 lockstep 13-wave blocks.
//  - double-buffered tile -> ONE barrier per iteration; ds_write of next tile
//    right after the barrier from registers loaded a full iteration earlier.
//  - global prefetch 2 groups deep; stores overlap the 25-tap compute.
// Staging stays fp16 x 8 images (uint4/pixel), taps stay base+immediate
// ds_read_b128 into a zero-padded halo tile (OOB == exact 0 == in_b mask).
__global__ __launch_bounds__(BLOCK, 7) void axs_89807766159734_kernel(
    const float* __restrict__ x, const float* __restrict__ pos2d,
    const float* __restrict__ weight, float* __restrict__ out,
    int nGroups, int slices)
{
    __shared__ uint4 tile[2][TSLOTS];

    const int tid  = threadIdx.x;
    const int band = blockIdx.x & 1;           // 0: rows 0..13, 1: rows 14..27
    const int s0   = blockIdx.x >> 1;

    // zero both tiles once (halo persists; staged rows rewritten every iter)
    for (int i = tid; i < 2 * TSLOTS; i += BLOCK)
        ((uint4*)tile)[i] = make_uint4(0u, 0u, 0u, 0u);

    // ---- 25 coefficients as named scalars + window base byte offset ----
    const bool act = tid < 392;
    const int P = band * 392 + tid;            // this thread's output pixel
    float c00=0,c01=0,c02=0,c03=0,c04=0,
          c10=0,c11=0,c12=0,c13=0,c14=0,
          c20=0,c21=0,c22=0,c23=0,c24=0,
          c30=0,c31=0,c32=0,c33=0,c34=0,
          c40=0,c41=0,c42=0,c43=0,c44=0;
    int base = 0;
    if (act) {
        const float p0 = pos2d[2 * P], p1 = pos2d[2 * P + 1];
        const float sw = fmaxf(weight[P], 0.0f);       // relu(weight) folded in
        const float r0 = rintf(p0), r1 = rintf(p1);    // rintf == jnp.round
        const int i0 = (int)r0, i1 = (int)r1;
        const float f0 = r0 - p0, f1 = r1 - p1;

        const float d0m2 = f0 - 2.f, d0m1 = f0 - 1.f, d0p1 = f0 + 1.f, d0p2 = f0 + 2.f;
        const float e0m2 = (i0 - 2 >= 0 && i0 - 2 < HH) ? sw * __expf(-0.5f * d0m2 * d0m2) : 0.f;
        const float e0m1 = (i0 - 1 >= 0 && i0 - 1 < HH) ? sw * __expf(-0.5f * d0m1 * d0m1) : 0.f;
        const float e0z  = (i0     >= 0 && i0     < HH) ? sw * __expf(-0.5f * f0   * f0  ) : 0.f;
        const float e0p1 = (i0 + 1 >= 0 && i0 + 1 < HH) ? sw * __expf(-0.5f * d0p1 * d0p1) : 0.f;
        const float e0p2 = (i0 + 2 >= 0 && i0 + 2 < HH) ? sw * __expf(-0.5f * d0p2 * d0p2) : 0.f;

        const float d1m2 = f1 - 2.f, d1m1 = f1 - 1.f, d1p1 = f1 + 1.f, d1p2 = f1 + 2.f;
        const float e1m2 = (i1 - 2 >= 0 && i1 - 2 < WW) ? __expf(-0.5f * d1m2 * d1m2) : 0.f;
        const float e1m1 = (i1 - 1 >= 0 && i1 - 1 < WW) ? __expf(-0.5f * d1m1 * d1m1) : 0.f;
        const float e1z  = (i1     >= 0 && i1     < WW) ? __expf(-0.5f * f1   * f1  ) : 0.f;
        const float e1p1 = (i1 + 1 >= 0 && i1 + 1 < WW) ? __expf(-0.5f * d1p1 * d1p1) : 0.f;
        const float e1p2 = (i1 + 2 >= 0 && i1 + 2 < WW) ? __expf(-0.5f * d1p2 * d1p2) : 0.f;

        c00 = e0m2*e1m2; c01 = e0m2*e1m1; c02 = e0m2*e1z; c03 = e0m2*e1p1; c04 = e0m2*e1p2;
        c10 = e0m1*e1m2; c11 = e0m1*e1m1; c12 = e0m1*e1z; c13 = e0m1*e1p1; c14 = e0m1*e1p2;
        c20 = e0z *e1m2; c21 = e0z *e1m1; c22 = e0z *e1z; c23 = e0z *e1p1; c24 = e0z *e1p2;
        c30 = e0p1*e1m2; c31 = e0p1*e1m1; c32 = e0p1*e1z; c33 = e0p1*e1p1; c34 = e0p1*e1p2;
        c40 = e0p2*e1m2; c41 = e0p2*e1m1; c42 = e0p2*e1z; c43 = e0p2*e1p1; c44 = e0p2*e1p2;

        // addressing clamp: band tile covers src rows [-4..19] (b0) / [8..31] (b1);
        // row clamp to [A0MIN..A0MAX] only engages at jitter |0.5N| > 3.5 (P~0);
        // col clamp engages only where e1 coefs are already 0.
        const int A0MIN = band ? 10 : -2, A0MAX = band ? 29 : 17;
        const int a0c = min(max(i0, A0MIN), A0MAX);
        const int a1c = min(max(i1, -2), WW + 1);
        const int trow = band ? (a0c - 10) : (a0c + 2);   // window-start tile row
        base = (trow * PSTRIDE + (a1c + 2)) * 16;
    }

    // ---- staging assignment: 560 src pixels (20 rows) per band ----
    const int q1 = tid;                               // src-slot index 0..447
    const bool st2 = (tid >= 336);                    // lanes 336..447 double-stage
    const int q2 = tid + 112;                         // 448..559 (when st2)
    const int P1 = q1 + band * 224;                   // global pixel of q1
    const int P2 = q2 + band * 224;
    const int rowoff = band ? 0 : 4;                  // tile row of src row
    const int slot1 = (q1 / 28 + rowoff) * PSTRIDE + (q1 % 28) + 4;
    const int slot2 = (q2 / 28 + rowoff) * PSTRIDE + (q2 % 28) + 4;

    float v0=0,v1=0,v2=0,v3=0,v4=0,v5=0,v6=0,v7=0;    // staging regs, pixel q1
    float u0=0,u1=0,u2=0,u3=0,u4=0,u5=0,u6=0,u7=0;    // staging regs, pixel q2

#define LOADR(G) do {                                                     \
        const size_t b8 = (size_t)(G) * 8u * NPIX;                        \
        v0 = x[b8 + P1];            v1 = x[b8 + NPIX + P1];               \
        v2 = x[b8 + 2*NPIX + P1];   v3 = x[b8 + 3*NPIX + P1];             \
        v4 = x[b8 + 4*NPIX + P1];   v5 = x[b8 + 5*NPIX + P1];             \
        v6 = x[b8 + 6*NPIX + P1];   v7 = x[b8 + 7*NPIX + P1];             \
        if (st2) {                                                        \
            u0 = x[b8 + P2];            u1 = x[b8 + NPIX + P2];           \
            u2 = x[b8 + 2*NPIX + P2];   u3 = x[b8 + 3*NPIX + P2];         \
            u4 = x[b8 + 4*NPIX + P2];   u5 = x[b8 + 5*NPIX + P2];         \
            u6 = x[b8 + 6*NPIX + P2];   u7 = x[b8 + 7*NPIX + P2];         \
        } } while (0)

#define WRITET(TP) do {                                                   \
        uint4 pk;                                                         \
        pk.x = __builtin_bit_cast(unsigned int, __floats2half2_rn(v0, v1)); \
        pk.y = __builtin_bit_cast(unsigned int, __floats2half2_rn(v2, v3)); \
        pk.z = __builtin_bit_cast(unsigned int, __floats2half2_rn(v4, v5)); \
        pk.w = __builtin_bit_cast(unsigned int, __floats2half2_rn(v6, v7)); \
        (TP)[slot1] = pk;                                                 \
        if (st2) {                                                        \
            uint4 pku;                                                    \
            pku.x = __builtin_bit_cast(unsigned int, __floats2half2_rn(u0, u1)); \
            pku.y = __builtin_bit_cast(unsigned int, __floats2half2_rn(u2, u3)); \
            pku.z = __builtin_bit_cast(unsigned int, __floats2half2_rn(u4, u5)); \
            pku.w = __builtin_bit_cast(unsigned int, __floats2half2_rn(u6, u7)); \
            (TP)[slot2] = pku;                                            \
        } } while (0)

    // ---- prologue: tile0 <- group s0, regs <- group s0+slices ----
    int g = s0;
    if (g < nGroups) LOADR(g);
    __syncthreads();                              // zero-fill visible
    if (g < nGroups) WRITET(tile[0]);
    {
        const int gl = g + slices;
        if (gl < nGroups) LOADR(gl);
    }

    int cur = 0;
    for (; g < nGroups; g += slices) {
        __syncthreads();            // tile[cur] visible; tile[cur^1] reads done

        const int gw = g + slices;          // group whose data sits in regs
        if (gw < nGroups) WRITET(tile[cur ^ 1]);
        const int gp = g + 2 * slices;      // issue next prefetch (2 deep)
        if (gp < nGroups) LOADR(gp);

        if (act) {
            float a0=0,a1=0,a2=0,a3=0,a4=0,a5=0,a6=0,a7=0;
            const char* bp = (const char*)(tile[cur]) + base;
#define TAP(I, J, C) do {                                                    \
            const uint4 tv = *(const uint4*)(bp + ((I) * PSTRIDE + (J)) * 16); \
            const __half2 h0 = __builtin_bit_cast(__half2, tv.x);            \
            const __half2 h1 = __builtin_bit_cast(__half2, tv.y);            \
            const __half2 h2 = __builtin_bit_cast(__half2, tv.z);            \
            const __half2 h3 = __builtin_bit_cast(__half2, tv.w);            \
            a0 = fmaf(C, __low2float(h0), a0);  a1 = fmaf(C, __high2float(h0), a1); \
            a2 = fmaf(C, __low2float(h1), a2);  a3 = fmaf(C, __high2float(h1), a3); \
            a4 = fmaf(C, __low2float(h2), a4);  a5 = fmaf(C, __high2float(h2), a5); \
            a6 = fmaf(C, __low2float(h3), a6);  a7 = fmaf(C, __high2float(h3), a7); \
        } while (0)
            TAP(0,0,c00); TAP(0,1,c01); TAP(0,2,c02); TAP(0,3,c03); TAP(0,4,c04);
            TAP(1,0,c10); TAP(1,1,c11); TAP(1,2,c12); TAP(1,3,c13); TAP(1,4,c14);
            TAP(2,0,c20); TAP(2,1,c21); TAP(2,2,c22); TAP(2,3,c23); TAP(2,4,c24);
            TAP(3,0,c30); TAP(3,1,c31); TAP(3,2,c32); TAP(3,3,c33); TAP(3,4,c34);
            TAP(4,0,c40); TAP(4,1,c41); TAP(4,2,c42); TAP(4,3,c43); TAP(4,4,c44);
#undef TAP
            const size_t b8 = (size_t)g * 8u * NPIX;
            out[b8 + P]          = a0;  out[b8 + NPIX + P]   = a1;
            out[b8 + 2*NPIX + P] = a2;  out[b8 + 3*NPIX + P] = a3;
            out[b8 + 4*NPIX + P] = a4;  out[b8 + 5*NPIX + P] = a5;
            out[b8 + 6*NPIX + P] = a6;  out[b8 + 7*NPIX + P] = a7;
        }
        cur ^= 1;
    }
#undef LOADR
#undef WRITET
}

extern "C" void kernel_launch(void* const* d_in, const int* in_sizes, int n_in,
                              void* d_out, int out_size, void* d_ws, size_t ws_size,
                              hipStream_t stream) {
    const float* x      = (const float*)d_in[0];   // (B,1,28,28) fp32
    const float* pos2d  = (const float*)d_in[1];   // (28,28,2)   fp32
    const float* weight = (const float*)d_in[2];   // (28,28)     fp32
    float* out = (float*)d_out;

    const int B = in_sizes[0] / NPIX;              // 32768
    const int nGroups = B / 8;                     // 4096
    const int slices = nGroups < 512 ? nGroups : 512;
    const int blocks = 2 * slices;                 // 1024 = 4 blocks/CU, 28 waves

    hipLaunchKernelGGL(axs_89807766159734_kernel, dim3(blocks), dim3(BLOCK), 0, stream,
                       x, pos2d, weight, out, nGroups, slices);
}